// Round 9
// baseline (27.163 us; speedup 1.0000x reference)
//
#include <hip/hip_runtime.h>

typedef float  f32x4  __attribute__((ext_vector_type(4)));
typedef short  bf16x8 __attribute__((ext_vector_type(8)));

#define Bb 256

// packed f32->bf16 (RNE), gfx950
__device__ __forceinline__ uint cvtpk(float lo, float hi) {
    uint r;
    asm("v_cvt_pk_bf16_f32 %0, %1, %2" : "=v"(r) : "v"(lo), "v"(hi));
    return r;
}
__device__ __forceinline__ ushort f2b1(float v) { return (ushort)cvtpk(v, v); }
__device__ __forceinline__ float bflo(uint u) { return __uint_as_float(u << 16); }
__device__ __forceinline__ float bfhi(uint u) { return __uint_as_float(u & 0xffff0000u); }

__device__ __forceinline__ void gl_lds16(const void* g, void* l) {
    __builtin_amdgcn_global_load_lds(
        (const __attribute__((address_space(1))) unsigned int*)g,
        (__attribute__((address_space(3))) unsigned int*)l, 16, 0, 0);
}

union U8 { uint u[4]; bf16x8 v; };

// ===================== prep: build bf16 LDS images in ws =====================
__global__ __launch_bounds__(256) void gcm_prep(
    const float* __restrict__ obs, const float* __restrict__ enc_w,
    const float* __restrict__ gate_w1, const float* __restrict__ msg_w1,
    const float* __restrict__ msg_w2,
    ushort* __restrict__ obs_bf, ushort* __restrict__ wimg)
{
    const int bid = blockIdx.x, t = threadIdx.x;
    if (bid < 1024) {
        const int G  = bid * 256 + t;       // 0..262143, 8 elems each
        const int e0 = G * 8;
        const int b  = e0 >> 13;
        const int r  = (e0 >> 7) & 63;
        const int d0 = e0 & 127;
        const int ds = d0 ^ ((r & 7) << 3);
        const float* src = obs + (((size_t)b * 64 + r) * 128 + ds);
        float4 f0 = *(const float4*)src;
        float4 f1 = *(const float4*)(src + 4);
        uint4 o;
        o.x = cvtpk(f0.x, f0.y); o.y = cvtpk(f0.z, f0.w);
        o.z = cvtpk(f1.x, f1.y); o.w = cvtpk(f1.z, f1.w);
        *(uint4*)(obs_bf + e0) = o;
    } else {
        const int G  = (bid - 1024) * 256 + t;   // 0..3071
        const int e0 = G * 8;
        float v[8];
        if (e0 < 8192) {
            const int n  = e0 >> 7;
            const int k0 = (e0 & 127) ^ ((n & 7) << 3);
            #pragma unroll
            for (int j = 0; j < 8; ++j) v[j] = enc_w[(k0 + j) * 64 + n];
        } else {
            const int e  = e0 - 8192;
            const int n  = e >> 6;
            const int k0 = (e & 63) ^ ((n & 7) << 3);
            const float* base; int col;
            if (n < 64)       { base = gate_w1;           col = n;       }
            else if (n < 128) { base = gate_w1 + 64 * 64; col = n - 64;  }
            else if (n < 192) { base = msg_w1;            col = n - 128; }
            else              { base = msg_w2;            col = n - 192; }
            #pragma unroll
            for (int j = 0; j < 8; ++j) v[j] = base[(k0 + j) * 64 + col];
        }
        uint4 o;
        o.x = cvtpk(v[0], v[1]); o.y = cvtpk(v[2], v[3]);
        o.z = cvtpk(v[4], v[5]); o.w = cvtpk(v[6], v[7]);
        *(uint4*)(wimg + e0) = o;
    }
}

// ===================== KA: P1-P3 for 32 rows (row-local, no duplication) =====
// grid 2*Bb: block = (batch, row-half). 64KB LDS -> 2 blocks/CU.
__global__ __launch_bounds__(512, 4) void gcm_ka(
    const ushort* __restrict__ obs_bf, const ushort* __restrict__ wimg,
    const float* __restrict__ enc_b, const float* __restrict__ gate_b1,
    const float* __restrict__ msg_b1, const float* __restrict__ msg_b2,
    ushort* __restrict__ gi_ws, ushort* __restrict__ gj_ws,
    ushort* __restrict__ msgT_ws)
{
    const int bid = blockIdx.x;
    const int bb  = bid >> 1;
    const int hR  = bid & 1;            // rows hR*32 .. hR*32+31
    const int t    = threadIdx.x;
    const int lane = t & 63;
    const int wv   = t >> 6;            // 0..7
    const int lr   = lane & 15;
    const int lg   = lane >> 4;
    const int rt   = wv >> 2;           // 0..1 local row-tile
    const int ct   = wv & 3;            // 0..3 col-tile

    __shared__ __align__(16) char arena[65536];
    ushort* s_obs   = (ushort*)(arena);            //  8K [r<32][d<128] swz ^(r&7)<<3
    ushort* s_encwT = (ushort*)(arena + 8192);     // 16K [n<64][k<128] swz
    ushort* s_wT    = (ushort*)(arena + 24576);    // 32K [n<256][k<64] swz
    ushort* s_enc   = (ushort*)(arena + 57344);    //  4K [r<32][h<64] swz
    ushort* s_msgh  = (ushort*)(arena + 61440);    //  4K [r<32][h<64] swz

    // ---- staging: 7 global_load_lds per wave ----
    {
        const ushort* ob = obs_bf + (size_t)bb * 8192 + hR * 4096 + wv * 512 + lane * 8;
        gl_lds16(ob, arena + wv * 1024);
        #pragma unroll
        for (int i = 0; i < 2; ++i) {
            const int idx = wv * 2 + i;            // 0..15
            gl_lds16(wimg + idx * 512 + lane * 8, arena + 8192 + idx * 1024);
        }
        #pragma unroll
        for (int i = 0; i < 4; ++i) {
            const int idx = wv * 4 + i;            // 0..31
            gl_lds16(wimg + 8192 + idx * 512 + lane * 8, arena + 24576 + idx * 1024);
        }
    }
    __syncthreads();   // B1

    // ---------- P1: enc = relu(obs @ enc_w + b); wave tile (rt, ct) ----------
    {
        f32x4 acc = (f32x4){0.f, 0.f, 0.f, 0.f};
        const int arow = rt * 16 + lr;             // local 0..31
        const int n = ct * 16 + lr;
        #pragma unroll
        for (int ks = 0; ks < 4; ++ks) {
            const int k0 = ks * 32 + lg * 8;
            bf16x8 a  = *(const bf16x8*)(s_obs + ((arow * 128 + k0) ^ ((arow & 7) << 3)));
            bf16x8 bf = *(const bf16x8*)(s_encwT + ((n * 128 + k0) ^ ((n & 7) << 3)));
            acc = __builtin_amdgcn_mfma_f32_16x16x32_bf16(a, bf, acc, 0, 0, 0);
        }
        const float be = enc_b[n];
        float v0 = fmaxf(acc[0] + be, 0.f), v1 = fmaxf(acc[1] + be, 0.f);
        float v2 = fmaxf(acc[2] + be, 0.f), v3 = fmaxf(acc[3] + be, 0.f);
        uint pA = cvtpk(v0, v1), pB = cvtpk(v2, v3);
        const int rb = rt * 16 + lg * 4;
        s_enc[((rb + 0) * 64 + n) ^ (((rb + 0) & 7) << 3)] = (ushort)pA;
        s_enc[((rb + 1) * 64 + n) ^ (((rb + 1) & 7) << 3)] = (ushort)(pA >> 16);
        s_enc[((rb + 2) * 64 + n) ^ (((rb + 2) & 7) << 3)] = (ushort)pB;
        s_enc[((rb + 3) * 64 + n) ^ (((rb + 3) & 7) << 3)] = (ushort)(pB >> 16);
    }
    __syncthreads();   // B2

    // ---------- P2: [gi|gj|msgh] = enc @ [wi|wj|mw1]; wave: rt, 3 col-tiles ----
    {
        f32x4 acc[3];
        #pragma unroll
        for (int q = 0; q < 3; ++q) acc[q] = (f32x4){0.f, 0.f, 0.f, 0.f};
        const int arow = rt * 16 + lr;
        #pragma unroll
        for (int ks = 0; ks < 2; ++ks) {
            const int k0 = ks * 32 + lg * 8;
            bf16x8 a = *(const bf16x8*)(s_enc + ((arow * 64 + k0) ^ ((arow & 7) << 3)));
            #pragma unroll
            for (int q = 0; q < 3; ++q) {
                const int n = (ct * 3 + q) * 16 + lr;
                bf16x8 bf = *(const bf16x8*)(s_wT + ((n * 64 + k0) ^ ((n & 7) << 3)));
                acc[q] = __builtin_amdgcn_mfma_f32_16x16x32_bf16(a, bf, acc[q], 0, 0, 0);
            }
        }
        const int rb = rt * 16 + lg * 4;           // local
        #pragma unroll
        for (int q = 0; q < 3; ++q) {
            const int nfull = (ct * 3 + q) * 16;
            const int cc = nfull + lr;
            if (nfull < 64) {                      // gi -> global bf16 [i][h]
                #pragma unroll
                for (int rr = 0; rr < 4; ++rr)
                    gi_ws[(size_t)bb * 4096 + (hR * 32 + rb + rr) * 64 + cc] = f2b1(acc[q][rr]);
            } else if (nfull < 128) {              // gj + b1 -> global bf16 [j][h]
                const float b1 = gate_b1[cc - 64];
                #pragma unroll
                for (int rr = 0; rr < 4; ++rr)
                    gj_ws[(size_t)bb * 4096 + (hR * 32 + rb + rr) * 64 + (cc - 64)] = f2b1(acc[q][rr] + b1);
            } else {                               // msgh -> LDS bf16 swz
                const float bm = msg_b1[cc - 128];
                float v0 = fmaxf(acc[q][0] + bm, 0.f), v1 = fmaxf(acc[q][1] + bm, 0.f);
                float v2 = fmaxf(acc[q][2] + bm, 0.f), v3 = fmaxf(acc[q][3] + bm, 0.f);
                uint pA = cvtpk(v0, v1), pB = cvtpk(v2, v3);
                const int c2 = cc - 128;
                s_msgh[((rb + 0) * 64 + c2) ^ (((rb + 0) & 7) << 3)] = (ushort)pA;
                s_msgh[((rb + 1) * 64 + c2) ^ (((rb + 1) & 7) << 3)] = (ushort)(pA >> 16);
                s_msgh[((rb + 2) * 64 + c2) ^ (((rb + 2) & 7) << 3)] = (ushort)pB;
                s_msgh[((rb + 3) * 64 + c2) ^ (((rb + 3) & 7) << 3)] = (ushort)(pB >> 16);
            }
        }
    }
    __syncthreads();   // B3

    // ---------- P3: msg = msgh @ mw2 + b2 -> msgT_ws swizzled image [h][j] ----
    {
        f32x4 acc = (f32x4){0.f, 0.f, 0.f, 0.f};
        const int arow = rt * 16 + lr;
        const int nn3 = 192 + ct * 16 + lr;
        #pragma unroll
        for (int ks = 0; ks < 2; ++ks) {
            const int k0 = ks * 32 + lg * 8;
            bf16x8 a  = *(const bf16x8*)(s_msgh + ((arow * 64 + k0) ^ ((arow & 7) << 3)));
            bf16x8 bf = *(const bf16x8*)(s_wT + ((nn3 * 64 + k0) ^ ((nn3 & 7) << 3)));
            acc = __builtin_amdgcn_mfma_f32_16x16x32_bf16(a, bf, acc, 0, 0, 0);
        }
        const int h  = ct * 16 + lr;
        const int jg = hR * 32 + rt * 16 + lg * 4;   // 4 consecutive j (global)
        const float bm2 = msg_b2[h];
        uint pA = cvtpk(acc[0] + bm2, acc[1] + bm2);
        uint pB = cvtpk(acc[2] + bm2, acc[3] + bm2);
        const int e = (h * 64 + jg) ^ ((h & 7) << 3);
        *(uint*)(msgT_ws + (size_t)bb * 4096 + e)     = pA;
        *(uint*)(msgT_ws + (size_t)bb * 4096 + e + 2) = pB;
    }
}

// ===================== KB: gates + P5 for 32 rows =====================
// grid 2*Bb, 512 thr, 12KB LDS -> up to 4 blocks/CU (thread-limited).
__global__ __launch_bounds__(512, 4) void gcm_kb(
    const float* __restrict__ gate_w2, const float* __restrict__ gate_b2,
    const ushort* __restrict__ gi_ws, const ushort* __restrict__ gj_ws,
    const ushort* __restrict__ msgT_ws, float* __restrict__ out)
{
    const int bid = blockIdx.x;
    const int bb  = bid >> 1;
    const int hR  = bid & 1;
    const int t    = threadIdx.x;
    const int lane = t & 63;
    const int wv   = t >> 6;            // 0..7
    const int lr   = lane & 15;
    const int lg   = lane >> 4;

    __shared__ __align__(16) char karena[12288];
    ushort* s_msgT   = (ushort*)(karena);          // 8K [h][j] swz image
    ushort* s_gatesb = (ushort*)(karena + 8192);   // 4K [i_local<32][j<64] swz

    // stage msgT image (lands during gates; drained by the barrier below)
    gl_lds16(msgT_ws + (size_t)bb * 4096 + wv * 512 + lane * 8, karena + wv * 1024);

    // gj row (j = lane) -> f32 in VGPRs
    float gjv[64];
    {
        const ushort* gp = gj_ws + (size_t)bb * 4096 + lane * 64;
        #pragma unroll
        for (int c = 0; c < 8; ++c) {
            uint4 p = *(const uint4*)(gp + c * 8);
            gjv[c * 8 + 0] = bflo(p.x); gjv[c * 8 + 1] = bfhi(p.x);
            gjv[c * 8 + 2] = bflo(p.y); gjv[c * 8 + 3] = bfhi(p.y);
            gjv[c * 8 + 4] = bflo(p.z); gjv[c * 8 + 5] = bfhi(p.z);
            gjv[c * 8 + 6] = bflo(p.w); gjv[c * 8 + 7] = bfhi(p.w);
        }
    }
    const float b2v = gate_b2[0];

    // gates: 4 rows/wave; gi + w2 via the scalar pipe
    #pragma unroll
    for (int r = 0; r < 4; ++r) {
        const int lrow = wv * 4 + r;               // local 0..31
        const int grow = __builtin_amdgcn_readfirstlane(hR * 32 + lrow);
        const uint* gip = (const uint*)(gi_ws + (size_t)bb * 4096 + grow * 64);
        float acc = 0.f;
        #pragma unroll
        for (int c = 0; c < 32; ++c) {
            const uint p = gip[c];                 // uniform -> s_load
            acc = fmaf(fmaxf(bflo(p) + gjv[2 * c],     0.f), gate_w2[2 * c],     acc);
            acc = fmaf(fmaxf(bfhi(p) + gjv[2 * c + 1], 0.f), gate_w2[2 * c + 1], acc);
        }
        const float g = 1.f / (1.f + __expf(-(acc + b2v)));
        s_gatesb[(lrow * 64 + lane) ^ ((lrow & 7) << 3)] = f2b1(g);
    }
    __syncthreads();   // gates + staged msgT ready

    // P5: enhanced = gates @ msg (MFMA); 32 rows, wave tile (rtl, ctl)
    {
        const int rtl = wv >> 2, ctl = wv & 3;
        f32x4 acc = (f32x4){0.f, 0.f, 0.f, 0.f};
        const int arow = rtl * 16 + lr;            // local row
        const int n = ctl * 16 + lr;               // h
        #pragma unroll
        for (int ks = 0; ks < 2; ++ks) {
            const int k0 = ks * 32 + lg * 8;
            bf16x8 a  = *(const bf16x8*)(s_gatesb + ((arow * 64 + k0) ^ ((arow & 7) << 3)));
            bf16x8 bf = *(const bf16x8*)(s_msgT   + ((n * 64 + k0) ^ ((n & 7) << 3)));
            acc = __builtin_amdgcn_mfma_f32_16x16x32_bf16(a, bf, acc, 0, 0, 0);
        }
        const int rb = hR * 32 + rtl * 16 + lg * 4;
        #pragma unroll
        for (int rr = 0; rr < 4; ++rr)
            out[((size_t)bb * 64 + rb + rr) * 64 + n] = acc[rr];
    }
}

// ============================ Fallback (R3, 21.3us) ============================
__global__ __launch_bounds__(1024) void gcm_fb(
    const float* __restrict__ obs, const float* __restrict__ enc_w,
    const float* __restrict__ enc_b, const float* __restrict__ gate_w1,
    const float* __restrict__ gate_b1, const float* __restrict__ gate_w2,
    const float* __restrict__ gate_b2, const float* __restrict__ msg_w1,
    const float* __restrict__ msg_b1, const float* __restrict__ msg_w2,
    const float* __restrict__ msg_b2, float* __restrict__ out)
{
    const int bb   = blockIdx.x;
    const int t    = threadIdx.x;
    const int lane = t & 63;
    const int wv   = t >> 6;
    const int lr   = lane & 15;
    const int lg   = lane >> 4;
    const int rt   = wv & 3;
    const int ct   = wv >> 2;

    __shared__ __align__(16) ushort s_encwT[64 * 128];
    __shared__ __align__(16) ushort s_wT[256 * 64];
    __shared__ __align__(16) ushort s_enc[64 * 64];
    __shared__ __align__(16) ushort s_msgh[64 * 64];
    __shared__ __align__(16) ushort s_gatesb[64 * 64];
    __shared__ __align__(16) ushort s_msgT[64 * 64];
    __shared__ __align__(16) float  s_gi[64 * 64];
    __shared__ __align__(16) float  s_gj[64 * 64];
    __shared__ __align__(16) float  s_w2[64];

    float4 pf[8];
    {
        const float* ob = obs + ((size_t)bb * 64 + rt * 16 + lr) * 128 + lg * 8;
        #pragma unroll
        for (int ks = 0; ks < 4; ++ks) {
            pf[2 * ks]     = *(const float4*)(ob + ks * 32);
            pf[2 * ks + 1] = *(const float4*)(ob + ks * 32 + 4);
        }
    }
    if (t < 64) s_w2[t] = gate_w2[t];
    #pragma unroll
    for (int it = 0; it < 2; ++it) {
        const int g  = t + it * 1024;
        const int k  = g >> 4;
        const int n0 = (g & 15) * 4;
        float4 w4 = *(const float4*)(enc_w + k * 64 + n0);
        uint pA = cvtpk(w4.x, w4.y), pB = cvtpk(w4.z, w4.w);
        s_encwT[((n0 + 0) * 128 + k) ^ (((n0 + 0) & 7) << 3)] = (ushort)pA;
        s_encwT[((n0 + 1) * 128 + k) ^ (((n0 + 1) & 7) << 3)] = (ushort)(pA >> 16);
        s_encwT[((n0 + 2) * 128 + k) ^ (((n0 + 2) & 7) << 3)] = (ushort)pB;
        s_encwT[((n0 + 3) * 128 + k) ^ (((n0 + 3) & 7) << 3)] = (ushort)(pB >> 16);
    }
    bf16x8 afrag[4];
    #pragma unroll
    for (int ks = 0; ks < 4; ++ks) {
        U8 u;
        u.u[0] = cvtpk(pf[2 * ks].x,     pf[2 * ks].y);
        u.u[1] = cvtpk(pf[2 * ks].z,     pf[2 * ks].w);
        u.u[2] = cvtpk(pf[2 * ks + 1].x, pf[2 * ks + 1].y);
        u.u[3] = cvtpk(pf[2 * ks + 1].z, pf[2 * ks + 1].w);
        afrag[ks] = u.v;
    }
    float4 pfw[4];
    {
        const int k  = t >> 4;
        const int n0 = (t & 15) * 4;
        pfw[0] = *(const float4*)(gate_w1 + k * 64 + n0);
        pfw[1] = *(const float4*)(gate_w1 + (64 + k) * 64 + n0);
        pfw[2] = *(const float4*)(msg_w1 + k * 64 + n0);
        pfw[3] = *(const float4*)(msg_w2 + k * 64 + n0);
    }
    __syncthreads();
    {
        f32x4 acc = (f32x4){0.f, 0.f, 0.f, 0.f};
        const int n = ct * 16 + lr;
        #pragma unroll
        for (int ks = 0; ks < 4; ++ks) {
            const int k0 = ks * 32 + lg * 8;
            bf16x8 bf = *(const bf16x8*)(s_encwT + ((n * 128 + k0) ^ ((n & 7) << 3)));
            acc = __builtin_amdgcn_mfma_f32_16x16x32_bf16(afrag[ks], bf, acc, 0, 0, 0);
        }
        #pragma unroll
        for (int it = 0; it < 4; ++it) {
            const int k  = t >> 4;
            const int n0 = it * 64 + (t & 15) * 4;
            uint pA = cvtpk(pfw[it].x, pfw[it].y), pB = cvtpk(pfw[it].z, pfw[it].w);
            s_wT[((n0 + 0) * 64 + k) ^ (((n0 + 0) & 7) << 3)] = (ushort)pA;
            s_wT[((n0 + 1) * 64 + k) ^ (((n0 + 1) & 7) << 3)] = (ushort)(pA >> 16);
            s_wT[((n0 + 2) * 64 + k) ^ (((n0 + 2) & 7) << 3)] = (ushort)pB;
            s_wT[((n0 + 3) * 64 + k) ^ (((n0 + 3) & 7) << 3)] = (ushort)(pB >> 16);
        }
        const float be = enc_b[n];
        float v0 = fmaxf(acc[0] + be, 0.f), v1 = fmaxf(acc[1] + be, 0.f);
        float v2 = fmaxf(acc[2] + be, 0.f), v3 = fmaxf(acc[3] + be, 0.f);
        uint pA = cvtpk(v0, v1), pB = cvtpk(v2, v3);
        const int rb = rt * 16 + lg * 4;
        s_enc[((rb + 0) * 64 + n) ^ (((rb + 0) & 7) << 3)] = (ushort)pA;
        s_enc[((rb + 1) * 64 + n) ^ (((rb + 1) & 7) << 3)] = (ushort)(pA >> 16);
        s_enc[((rb + 2) * 64 + n) ^ (((rb + 2) & 7) << 3)] = (ushort)pB;
        s_enc[((rb + 3) * 64 + n) ^ (((rb + 3) & 7) << 3)] = (ushort)(pB >> 16);
    }
    __syncthreads();
    {
        f32x4 acc[3];
        #pragma unroll
        for (int q = 0; q < 3; ++q) acc[q] = (f32x4){0.f, 0.f, 0.f, 0.f};
        const int arow = rt * 16 + lr;
        #pragma unroll
        for (int ks = 0; ks < 2; ++ks) {
            const int k0 = ks * 32 + lg * 8;
            bf16x8 a = *(const bf16x8*)(s_enc + ((arow * 64 + k0) ^ ((arow & 7) << 3)));
            #pragma unroll
            for (int q = 0; q < 3; ++q) {
                const int n = (ct * 3 + q) * 16 + lr;
                bf16x8 bf = *(const bf16x8*)(s_wT + ((n * 64 + k0) ^ ((n & 7) << 3)));
                acc[q] = __builtin_amdgcn_mfma_f32_16x16x32_bf16(a, bf, acc[q], 0, 0, 0);
            }
        }
        const int rb = rt * 16 + lg * 4;
        #pragma unroll
        for (int q = 0; q < 3; ++q) {
            const int nfull = (ct * 3 + q) * 16;
            const int cc = nfull + lr;
            if (nfull < 64) {
                #pragma unroll
                for (int rr = 0; rr < 4; ++rr) {
                    const int row = rb + rr;
                    s_gi[(row * 64 + cc) ^ ((row & 7) << 2)] = acc[q][rr];
                }
            } else if (nfull < 128) {
                const float b1 = gate_b1[cc - 64];
                #pragma unroll
                for (int rr = 0; rr < 4; ++rr) {
                    const int row = rb + rr;
                    s_gj[(row * 64 + (cc - 64)) ^ ((row & 7) << 2)] = acc[q][rr] + b1;
                }
            } else {
                const float bm = msg_b1[cc - 128];
                float v0 = fmaxf(acc[q][0] + bm, 0.f), v1 = fmaxf(acc[q][1] + bm, 0.f);
                float v2 = fmaxf(acc[q][2] + bm, 0.f), v3 = fmaxf(acc[q][3] + bm, 0.f);
                uint pA = cvtpk(v0, v1), pB = cvtpk(v2, v3);
                const int c2 = cc - 128;
                s_msgh[((rb + 0) * 64 + c2) ^ (((rb + 0) & 7) << 3)] = (ushort)pA;
                s_msgh[((rb + 1) * 64 + c2) ^ (((rb + 1) & 7) << 3)] = (ushort)(pA >> 16);
                s_msgh[((rb + 2) * 64 + c2) ^ (((rb + 2) & 7) << 3)] = (ushort)pB;
                s_msgh[((rb + 3) * 64 + c2) ^ (((rb + 3) & 7) << 3)] = (ushort)(pB >> 16);
            }
        }
    }
    __syncthreads();
    {
        f32x4 acc = (f32x4){0.f, 0.f, 0.f, 0.f};
        const int arow = rt * 16 + lr;
        const int nn3 = 192 + ct * 16 + lr;
        #pragma unroll
        for (int ks = 0; ks < 2; ++ks) {
            const int k0 = ks * 32 + lg * 8;
            bf16x8 a = *(const bf16x8*)(s_msgh + ((arow * 64 + k0) ^ ((arow & 7) << 3)));
            bf16x8 bf = *(const bf16x8*)(s_wT + ((nn3 * 64 + k0) ^ ((nn3 & 7) << 3)));
            acc = __builtin_amdgcn_mfma_f32_16x16x32_bf16(a, bf, acc, 0, 0, 0);
        }
        const int h  = ct * 16 + lr;
        const int jb = rt * 16 + lg * 4;
        const float bm2 = msg_b2[h];
        uint pA = cvtpk(acc[0] + bm2, acc[1] + bm2);
        uint pB = cvtpk(acc[2] + bm2, acc[3] + bm2);
        const int e = (h * 64 + jb) ^ ((h & 7) << 3);
        *(uint*)(s_msgT + e)     = pA;
        *(uint*)(s_msgT + e + 2) = pB;
    }
    {
        const int row0g = wv * 4;
        float ag[4] = {0.f, 0.f, 0.f, 0.f};
        #pragma unroll 4
        for (int h0 = 0; h0 < 64; h0 += 4) {
            float4 gj4 = *(const float4*)&s_gj[(lane * 64 + h0) ^ ((lane & 7) << 2)];
            float4 w24 = *(const float4*)&s_w2[h0];
            #pragma unroll
            for (int r = 0; r < 4; ++r) {
                const int row = row0g + r;
                float4 gi4 = *(const float4*)&s_gi[(row * 64 + h0) ^ ((row & 7) << 2)];
                ag[r] = fmaf(fmaxf(gi4.x + gj4.x, 0.f), w24.x, ag[r]);
                ag[r] = fmaf(fmaxf(gi4.y + gj4.y, 0.f), w24.y, ag[r]);
                ag[r] = fmaf(fmaxf(gi4.z + gj4.z, 0.f), w24.z, ag[r]);
                ag[r] = fmaf(fmaxf(gi4.w + gj4.w, 0.f), w24.w, ag[r]);
            }
        }
        const float b2v = gate_b2[0];
        #pragma unroll
        for (int r = 0; r < 4; ++r) {
            const int row = row0g + r;
            const float g = 1.f / (1.f + __expf(-(ag[r] + b2v)));
            s_gatesb[(row * 64 + lane) ^ ((row & 7) << 3)] = f2b1(g);
        }
    }
    __syncthreads();
    {
        const int rtl = wv >> 2;
        const int ctl = wv & 3;
        f32x4 acc = (f32x4){0.f, 0.f, 0.f, 0.f};
        const int arow = rtl * 16 + lr;
        const int n = ctl * 16 + lr;
        #pragma unroll
        for (int ks = 0; ks < 2; ++ks) {
            const int k0 = ks * 32 + lg * 8;
            bf16x8 a  = *(const bf16x8*)(s_gatesb + ((arow * 64 + k0) ^ ((arow & 7) << 3)));
            bf16x8 bf = *(const bf16x8*)(s_msgT   + ((n * 64 + k0) ^ ((n & 7) << 3)));
            acc = __builtin_amdgcn_mfma_f32_16x16x32_bf16(a, bf, acc, 0, 0, 0);
        }
        const int rb = rtl * 16 + lg * 4;
        #pragma unroll
        for (int rr = 0; rr < 4; ++rr)
            out[((size_t)bb * 64 + rb + rr) * 64 + n] = acc[rr];
    }
}

extern "C" void kernel_launch(void* const* d_in, const int* in_sizes, int n_in,
                              void* d_out, int out_size, void* d_ws, size_t ws_size,
                              hipStream_t stream) {
    const float* obs     = (const float*)d_in[0];
    const float* enc_w   = (const float*)d_in[1];
    const float* enc_b   = (const float*)d_in[2];
    const float* gate_w1 = (const float*)d_in[3];
    const float* gate_b1 = (const float*)d_in[4];
    const float* gate_w2 = (const float*)d_in[5];
    const float* gate_b2 = (const float*)d_in[6];
    const float* msg_w1  = (const float*)d_in[7];
    const float* msg_b1  = (const float*)d_in[8];
    const float* msg_w2  = (const float*)d_in[9];
    const float* msg_b2  = (const float*)d_in[10];
    float* out = (float*)d_out;

    const size_t obs_elems = (size_t)Bb * 64 * 128;       // 2,097,152 bf16
    const size_t w_elems   = 24576;
    const size_t per       = (size_t)Bb * 64 * 64;        // 1,048,576 bf16 each
    const size_t need = (obs_elems + w_elems + 3 * per) * sizeof(ushort);  // ~10.5 MB
    if (ws_size >= need) {
        ushort* obs_bf  = (ushort*)d_ws;
        ushort* wimg    = obs_bf + obs_elems;
        ushort* gi_ws   = wimg + w_elems;
        ushort* gj_ws   = gi_ws + per;
        ushort* msgT_ws = gj_ws + per;
        gcm_prep<<<1036, 256, 0, stream>>>(obs, enc_w, gate_w1, msg_w1, msg_w2,
                                           obs_bf, wimg);
        gcm_ka<<<2 * Bb, 512, 0, stream>>>(obs_bf, wimg, enc_b, gate_b1,
                                           msg_b1, msg_b2, gi_ws, gj_ws, msgT_ws);
        gcm_kb<<<2 * Bb, 512, 0, stream>>>(gate_w2, gate_b2, gi_ws, gj_ws,
                                           msgT_ws, out);
    } else {
        gcm_fb<<<Bb, 1024, 0, stream>>>(obs, enc_w, enc_b, gate_w1, gate_b1,
                                        gate_w2, gate_b2, msg_w1, msg_b1,
                                        msg_w2, msg_b2, out);
    }
}

// Round 10
// 21.312 us; speedup vs baseline: 1.2745x; 1.2745x over previous
//
#include <hip/hip_runtime.h>

typedef float  f32x4  __attribute__((ext_vector_type(4)));
typedef short  bf16x8 __attribute__((ext_vector_type(8)));

#define Bb 256

// packed f32->bf16 (RNE), gfx950
__device__ __forceinline__ uint cvtpk(float lo, float hi) {
    uint r;
    asm("v_cvt_pk_bf16_f32 %0, %1, %2" : "=v"(r) : "v"(lo), "v"(hi));
    return r;
}
__device__ __forceinline__ ushort f2b1(float v) { return (ushort)cvtpk(v, v); }
__device__ __forceinline__ float bflo(uint u) { return __uint_as_float(u << 16); }
__device__ __forceinline__ float bfhi(uint u) { return __uint_as_float(u & 0xffff0000u); }

__device__ __forceinline__ void gl_lds16(const void* g, void* l) {
    __builtin_amdgcn_global_load_lds(
        (const __attribute__((address_space(1))) unsigned int*)g,
        (__attribute__((address_space(3))) unsigned int*)l, 16, 0, 0);
}

union U8 { uint u[4]; bf16x8 v; };

// ===================== prep: build bf16 LDS images in ws =====================
__global__ __launch_bounds__(256) void gcm_prep(
    const float* __restrict__ obs, const float* __restrict__ enc_w,
    const float* __restrict__ gate_w1, const float* __restrict__ msg_w1,
    const float* __restrict__ msg_w2,
    ushort* __restrict__ obs_bf, ushort* __restrict__ wimg)
{
    const int bid = blockIdx.x, t = threadIdx.x;
    if (bid < 1024) {
        const int G  = bid * 256 + t;       // 0..262143, 8 elems each
        const int e0 = G * 8;
        const int b  = e0 >> 13;
        const int r  = (e0 >> 7) & 63;
        const int d0 = e0 & 127;
        const int ds = d0 ^ ((r & 7) << 3);
        const float* src = obs + (((size_t)b * 64 + r) * 128 + ds);
        float4 f0 = *(const float4*)src;
        float4 f1 = *(const float4*)(src + 4);
        uint4 o;
        o.x = cvtpk(f0.x, f0.y); o.y = cvtpk(f0.z, f0.w);
        o.z = cvtpk(f1.x, f1.y); o.w = cvtpk(f1.z, f1.w);
        *(uint4*)(obs_bf + e0) = o;
    } else {
        const int G  = (bid - 1024) * 256 + t;   // 0..3071
        const int e0 = G * 8;
        float v[8];
        if (e0 < 8192) {
            const int n  = e0 >> 7;
            const int k0 = (e0 & 127) ^ ((n & 7) << 3);
            #pragma unroll
            for (int j = 0; j < 8; ++j) v[j] = enc_w[(k0 + j) * 64 + n];
        } else {
            const int e  = e0 - 8192;
            const int n  = e >> 6;
            const int k0 = (e & 63) ^ ((n & 7) << 3);
            const float* base; int col;
            if (n < 64)       { base = gate_w1;           col = n;       }
            else if (n < 128) { base = gate_w1 + 64 * 64; col = n - 64;  }
            else if (n < 192) { base = msg_w1;            col = n - 128; }
            else              { base = msg_w2;            col = n - 192; }
            #pragma unroll
            for (int j = 0; j < 8; ++j) v[j] = base[(k0 + j) * 64 + col];
        }
        uint4 o;
        o.x = cvtpk(v[0], v[1]); o.y = cvtpk(v[2], v[3]);
        o.z = cvtpk(v[4], v[5]); o.w = cvtpk(v[6], v[7]);
        *(uint4*)(wimg + e0) = o;
    }
}

// ===================== main: fused P1..P5 =====================
__global__ __launch_bounds__(1024, 1) void gcm_main(
    ushort* __restrict__ obs_bf, const ushort* __restrict__ wimg,
    const float* __restrict__ enc_b, const float* __restrict__ gate_b1,
    const float* __restrict__ gate_w2, const float* __restrict__ gate_b2,
    const float* __restrict__ msg_b1, const float* __restrict__ msg_b2,
    float* __restrict__ out)
{
    const int bb   = blockIdx.x;
    const int t    = threadIdx.x;
    const int lane = t & 63;
    const int wv   = t >> 6;            // 0..15
    const int lr   = lane & 15;
    const int lg   = lane >> 4;
    const int rt   = wv & 3;
    const int ct   = wv >> 2;

    __shared__ __align__(16) char arena[114688];
    ushort* s_obs    = (ushort*)(arena);            // 16K [r<64][d<128] swz ^(r&7)<<3
    ushort* s_encwT  = (ushort*)(arena + 16384);    // 16K [n<64][k<128] swz
    ushort* s_wT     = (ushort*)(arena + 32768);    // 32K [n<256][k<64] swz
    ushort* s_enc    = (ushort*)(arena + 65536);    //  8K [r<64][h<64] swz
    ushort* s_msgh   = (ushort*)(arena + 73728);    //  8K
    float*  s_gj     = (float*) (arena + 81920);    // 16K [r<64][h<64] swz ^(r&7)<<2
    ushort* s_msgT   = (ushort*)(arena + 98304);    //  8K [h<64][j<64] swz
    ushort* s_gatesb = (ushort*)(arena + 106496);   //  8K [i<64][j<64] swz

    ushort* gi_ws = obs_bf + (size_t)bb * 8192;     // [i<64][h<64] bf16 (slice dead after B2)

    // ---- staging: obs, encwT first; wT last (stays in flight under P1) ----
    {
        const ushort* ob = obs_bf + (size_t)bb * 8192 + wv * 512 + lane * 8;
        gl_lds16(ob, arena + wv * 1024);
        const ushort* ew = wimg + wv * 512 + lane * 8;
        gl_lds16(ew, arena + 16384 + wv * 1024);
        const ushort* w0 = wimg + 8192 + wv * 512 + lane * 8;
        gl_lds16(w0, arena + 32768 + wv * 1024);
        const ushort* w1 = wimg + 8192 + (wv + 16) * 512 + lane * 8;
        gl_lds16(w1, arena + 32768 + (wv + 16) * 1024);
    }
    // B1: only obs + encwT must be resident; the 2 wT loads stay outstanding.
    asm volatile("s_waitcnt vmcnt(2)" ::: "memory");
    __builtin_amdgcn_s_barrier();
    __builtin_amdgcn_sched_barrier(0);

    // ---------- P1: enc = relu(obs @ enc_w + b); wave tile (rt, ct) ----------
    {
        f32x4 acc = (f32x4){0.f, 0.f, 0.f, 0.f};
        const int arow = rt * 16 + lr;
        const int n = ct * 16 + lr;
        #pragma unroll
        for (int ks = 0; ks < 4; ++ks) {
            const int k0 = ks * 32 + lg * 8;
            bf16x8 a  = *(const bf16x8*)(s_obs + ((arow * 128 + k0) ^ ((arow & 7) << 3)));
            bf16x8 bf = *(const bf16x8*)(s_encwT + ((n * 128 + k0) ^ ((n & 7) << 3)));
            acc = __builtin_amdgcn_mfma_f32_16x16x32_bf16(a, bf, acc, 0, 0, 0);
        }
        const float be = enc_b[n];
        float v0 = fmaxf(acc[0] + be, 0.f), v1 = fmaxf(acc[1] + be, 0.f);
        float v2 = fmaxf(acc[2] + be, 0.f), v3 = fmaxf(acc[3] + be, 0.f);
        uint pA = cvtpk(v0, v1), pB = cvtpk(v2, v3);
        const int rb = rt * 16 + lg * 4;
        s_enc[((rb + 0) * 64 + n) ^ (((rb + 0) & 7) << 3)] = (ushort)pA;
        s_enc[((rb + 1) * 64 + n) ^ (((rb + 1) & 7) << 3)] = (ushort)(pA >> 16);
        s_enc[((rb + 2) * 64 + n) ^ (((rb + 2) & 7) << 3)] = (ushort)pB;
        s_enc[((rb + 3) * 64 + n) ^ (((rb + 3) & 7) << 3)] = (ushort)(pB >> 16);
    }
    __syncthreads();   // B2: full drain (wT arrived during P1) + enc visible

    // ---------- P2: [gi|gj|msgh] = enc @ [wi|wj|mw1]; wave: rt, 3 col-tiles ----------
    {
        f32x4 acc[3];
        #pragma unroll
        for (int q = 0; q < 3; ++q) acc[q] = (f32x4){0.f, 0.f, 0.f, 0.f};
        const int arow = rt * 16 + lr;
        #pragma unroll
        for (int ks = 0; ks < 2; ++ks) {
            const int k0 = ks * 32 + lg * 8;
            bf16x8 a = *(const bf16x8*)(s_enc + ((arow * 64 + k0) ^ ((arow & 7) << 3)));
            #pragma unroll
            for (int q = 0; q < 3; ++q) {
                const int n = (ct * 3 + q) * 16 + lr;
                bf16x8 bf = *(const bf16x8*)(s_wT + ((n * 64 + k0) ^ ((n & 7) << 3)));
                acc[q] = __builtin_amdgcn_mfma_f32_16x16x32_bf16(a, bf, acc[q], 0, 0, 0);
            }
        }
        const int rb = rt * 16 + lg * 4;
        #pragma unroll
        for (int q = 0; q < 3; ++q) {
            const int nfull = (ct * 3 + q) * 16;
            const int cc = nfull + lr;
            if (nfull < 64) {                       // gi -> GLOBAL ws bf16 (for s_load)
                #pragma unroll
                for (int rr = 0; rr < 4; ++rr)
                    gi_ws[(rb + rr) * 64 + cc] = f2b1(acc[q][rr]);
            } else if (nfull < 128) {               // gj + b1 -> LDS f32 swz
                const float b1 = gate_b1[cc - 64];
                #pragma unroll
                for (int rr = 0; rr < 4; ++rr) {
                    const int row = rb + rr;
                    s_gj[(row * 64 + (cc - 64)) ^ ((row & 7) << 2)] = acc[q][rr] + b1;
                }
            } else {                                // msgh = relu(.+msg_b1) bf16 swz
                const float bm = msg_b1[cc - 128];
                float v0 = fmaxf(acc[q][0] + bm, 0.f), v1 = fmaxf(acc[q][1] + bm, 0.f);
                float v2 = fmaxf(acc[q][2] + bm, 0.f), v3 = fmaxf(acc[q][3] + bm, 0.f);
                uint pA = cvtpk(v0, v1), pB = cvtpk(v2, v3);
                const int c2 = cc - 128;
                s_msgh[((rb + 0) * 64 + c2) ^ (((rb + 0) & 7) << 3)] = (ushort)pA;
                s_msgh[((rb + 1) * 64 + c2) ^ (((rb + 1) & 7) << 3)] = (ushort)(pA >> 16);
                s_msgh[((rb + 2) * 64 + c2) ^ (((rb + 2) & 7) << 3)] = (ushort)pB;
                s_msgh[((rb + 3) * 64 + c2) ^ (((rb + 3) & 7) << 3)] = (ushort)(pB >> 16);
            }
        }
    }
    __syncthreads();   // B3: gj/msgh ready; gi stores drained (vmcnt(0) at barrier)

    // ---------- P3: msg = msgh @ mw2 + b2 -> s_msgT bf16 [h][j] ----------
    {
        f32x4 acc = (f32x4){0.f, 0.f, 0.f, 0.f};
        const int arow = rt * 16 + lr;
        const int nn3 = 192 + ct * 16 + lr;
        #pragma unroll
        for (int ks = 0; ks < 2; ++ks) {
            const int k0 = ks * 32 + lg * 8;
            bf16x8 a  = *(const bf16x8*)(s_msgh + ((arow * 64 + k0) ^ ((arow & 7) << 3)));
            bf16x8 bf = *(const bf16x8*)(s_wT + ((nn3 * 64 + k0) ^ ((nn3 & 7) << 3)));
            acc = __builtin_amdgcn_mfma_f32_16x16x32_bf16(a, bf, acc, 0, 0, 0);
        }
        const int h  = ct * 16 + lr;
        const int jb = rt * 16 + lg * 4;
        const float bm2 = msg_b2[h];
        uint pA = cvtpk(acc[0] + bm2, acc[1] + bm2);
        uint pB = cvtpk(acc[2] + bm2, acc[3] + bm2);
        const int e = (h * 64 + jb) ^ ((h & 7) << 3);
        *(uint*)(s_msgT + e)     = pA;
        *(uint*)(s_msgT + e + 2) = pB;
    }

    // ---------- gates: sigmoid(relu(gi[i]+gj[j]).w2 + b2); lane=j ----------
    // gi + w2 via scalar pipe; gj hoisted to VGPRs; float2 math (packed f32 ops).
    {
        const int row0g = wv * 4;
        float gjv[64];
        #pragma unroll
        for (int c4 = 0; c4 < 16; ++c4) {
            float4 g4 = *(const float4*)(s_gj + ((lane * 64 + c4 * 4) ^ ((lane & 7) << 2)));
            gjv[c4 * 4 + 0] = g4.x; gjv[c4 * 4 + 1] = g4.y;
            gjv[c4 * 4 + 2] = g4.z; gjv[c4 * 4 + 3] = g4.w;
        }
        const uint* gip0 = (const uint*)(gi_ws + __builtin_amdgcn_readfirstlane(row0g + 0) * 64);
        const uint* gip1 = (const uint*)(gi_ws + __builtin_amdgcn_readfirstlane(row0g + 1) * 64);
        const uint* gip2 = (const uint*)(gi_ws + __builtin_amdgcn_readfirstlane(row0g + 2) * 64);
        const uint* gip3 = (const uint*)(gi_ws + __builtin_amdgcn_readfirstlane(row0g + 3) * 64);
        const float2* w2p = (const float2*)gate_w2;         // uniform -> s_load
        float2 ag0 = {0.f, 0.f}, ag1 = {0.f, 0.f}, ag2 = {0.f, 0.f}, ag3 = {0.f, 0.f};
        #pragma unroll
        for (int c = 0; c < 32; ++c) {
            const float2 w22 = w2p[c];
            const float2 gj2 = {gjv[2 * c], gjv[2 * c + 1]};
            uint p;
            p = gip0[c];
            { float2 s = {bflo(p) + gj2.x, bfhi(p) + gj2.y};
              s.x = fmaxf(s.x, 0.f); s.y = fmaxf(s.y, 0.f);
              ag0.x = fmaf(s.x, w22.x, ag0.x); ag0.y = fmaf(s.y, w22.y, ag0.y); }
            p = gip1[c];
            { float2 s = {bflo(p) + gj2.x, bfhi(p) + gj2.y};
              s.x = fmaxf(s.x, 0.f); s.y = fmaxf(s.y, 0.f);
              ag1.x = fmaf(s.x, w22.x, ag1.x); ag1.y = fmaf(s.y, w22.y, ag1.y); }
            p = gip2[c];
            { float2 s = {bflo(p) + gj2.x, bfhi(p) + gj2.y};
              s.x = fmaxf(s.x, 0.f); s.y = fmaxf(s.y, 0.f);
              ag2.x = fmaf(s.x, w22.x, ag2.x); ag2.y = fmaf(s.y, w22.y, ag2.y); }
            p = gip3[c];
            { float2 s = {bflo(p) + gj2.x, bfhi(p) + gj2.y};
              s.x = fmaxf(s.x, 0.f); s.y = fmaxf(s.y, 0.f);
              ag3.x = fmaf(s.x, w22.x, ag3.x); ag3.y = fmaf(s.y, w22.y, ag3.y); }
        }
        const float b2v = gate_b2[0];
        float a0 = ag0.x + ag0.y, a1 = ag1.x + ag1.y;
        float a2 = ag2.x + ag2.y, a3 = ag3.x + ag3.y;
        float g0 = 1.f / (1.f + __expf(-(a0 + b2v)));
        float g1 = 1.f / (1.f + __expf(-(a1 + b2v)));
        float g2 = 1.f / (1.f + __expf(-(a2 + b2v)));
        float g3 = 1.f / (1.f + __expf(-(a3 + b2v)));
        s_gatesb[((row0g + 0) * 64 + lane) ^ (((row0g + 0) & 7) << 3)] = f2b1(g0);
        s_gatesb[((row0g + 1) * 64 + lane) ^ (((row0g + 1) & 7) << 3)] = f2b1(g1);
        s_gatesb[((row0g + 2) * 64 + lane) ^ (((row0g + 2) & 7) << 3)] = f2b1(g2);
        s_gatesb[((row0g + 3) * 64 + lane) ^ (((row0g + 3) & 7) << 3)] = f2b1(g3);
    }
    __syncthreads();   // B4: gates + msgT ready

    // ---------- P5: enhanced = gates @ msg (MFMA); wave tile ----------
    {
        const int rtl = wv >> 2;
        const int ctl = wv & 3;
        f32x4 acc = (f32x4){0.f, 0.f, 0.f, 0.f};
        const int arow = rtl * 16 + lr;
        const int n = ctl * 16 + lr;
        #pragma unroll
        for (int ks = 0; ks < 2; ++ks) {
            const int k0 = ks * 32 + lg * 8;
            bf16x8 a  = *(const bf16x8*)(s_gatesb + ((arow * 64 + k0) ^ ((arow & 7) << 3)));
            bf16x8 bf = *(const bf16x8*)(s_msgT   + ((n * 64 + k0) ^ ((n & 7) << 3)));
            acc = __builtin_amdgcn_mfma_f32_16x16x32_bf16(a, bf, acc, 0, 0, 0);
        }
        const int rb = rtl * 16 + lg * 4;
        #pragma unroll
        for (int rr = 0; rr < 4; ++rr)
            out[((size_t)bb * 64 + rb + rr) * 64 + n] = acc[rr];
    }
}

// ============================ Fallback (R3, 21.3us) ============================
__global__ __launch_bounds__(1024) void gcm_fb(
    const float* __restrict__ obs, const float* __restrict__ enc_w,
    const float* __restrict__ enc_b, const float* __restrict__ gate_w1,
    const float* __restrict__ gate_b1, const float* __restrict__ gate_w2,
    const float* __restrict__ gate_b2, const float* __restrict__ msg_w1,
    const float* __restrict__ msg_b1, const float* __restrict__ msg_w2,
    const float* __restrict__ msg_b2, float* __restrict__ out)
{
    const int bb   = blockIdx.x;
    const int t    = threadIdx.x;
    const int lane = t & 63;
    const int wv   = t >> 6;
    const int lr   = lane & 15;
    const int lg   = lane >> 4;
    const int rt   = wv & 3;
    const int ct   = wv >> 2;

    __shared__ __align__(16) ushort s_encwT[64 * 128];
    __shared__ __align__(16) ushort s_wT[256 * 64];
    __shared__ __align__(16) ushort s_enc[64 * 64];
    __shared__ __align__(16) ushort s_msgh[64 * 64];
    __shared__ __align__(16) ushort s_gatesb[64 * 64];
    __shared__ __align__(16) ushort s_msgT[64 * 64];
    __shared__ __align__(16) float  s_gi[64 * 64];
    __shared__ __align__(16) float  s_gj[64 * 64];
    __shared__ __align__(16) float  s_w2[64];

    float4 pf[8];
    {
        const float* ob = obs + ((size_t)bb * 64 + rt * 16 + lr) * 128 + lg * 8;
        #pragma unroll
        for (int ks = 0; ks < 4; ++ks) {
            pf[2 * ks]     = *(const float4*)(ob + ks * 32);
            pf[2 * ks + 1] = *(const float4*)(ob + ks * 32 + 4);
        }
    }
    if (t < 64) s_w2[t] = gate_w2[t];
    #pragma unroll
    for (int it = 0; it < 2; ++it) {
        const int g  = t + it * 1024;
        const int k  = g >> 4;
        const int n0 = (g & 15) * 4;
        float4 w4 = *(const float4*)(enc_w + k * 64 + n0);
        uint pA = cvtpk(w4.x, w4.y), pB = cvtpk(w4.z, w4.w);
        s_encwT[((n0 + 0) * 128 + k) ^ (((n0 + 0) & 7) << 3)] = (ushort)pA;
        s_encwT[((n0 + 1) * 128 + k) ^ (((n0 + 1) & 7) << 3)] = (ushort)(pA >> 16);
        s_encwT[((n0 + 2) * 128 + k) ^ (((n0 + 2) & 7) << 3)] = (ushort)pB;
        s_encwT[((n0 + 3) * 128 + k) ^ (((n0 + 3) & 7) << 3)] = (ushort)(pB >> 16);
    }
    bf16x8 afrag[4];
    #pragma unroll
    for (int ks = 0; ks < 4; ++ks) {
        U8 u;
        u.u[0] = cvtpk(pf[2 * ks].x,     pf[2 * ks].y);
        u.u[1] = cvtpk(pf[2 * ks].z,     pf[2 * ks].w);
        u.u[2] = cvtpk(pf[2 * ks + 1].x, pf[2 * ks + 1].y);
        u.u[3] = cvtpk(pf[2 * ks + 1].z, pf[2 * ks + 1].w);
        afrag[ks] = u.v;
    }
    float4 pfw[4];
    {
        const int k  = t >> 4;
        const int n0 = (t & 15) * 4;
        pfw[0] = *(const float4*)(gate_w1 + k * 64 + n0);
        pfw[1] = *(const float4*)(gate_w1 + (64 + k) * 64 + n0);
        pfw[2] = *(const float4*)(msg_w1 + k * 64 + n0);
        pfw[3] = *(const float4*)(msg_w2 + k * 64 + n0);
    }
    __syncthreads();
    {
        f32x4 acc = (f32x4){0.f, 0.f, 0.f, 0.f};
        const int n = ct * 16 + lr;
        #pragma unroll
        for (int ks = 0; ks < 4; ++ks) {
            const int k0 = ks * 32 + lg * 8;
            bf16x8 bf = *(const bf16x8*)(s_encwT + ((n * 128 + k0) ^ ((n & 7) << 3)));
            acc = __builtin_amdgcn_mfma_f32_16x16x32_bf16(afrag[ks], bf, acc, 0, 0, 0);
        }
        #pragma unroll
        for (int it = 0; it < 4; ++it) {
            const int k  = t >> 4;
            const int n0 = it * 64 + (t & 15) * 4;
            uint pA = cvtpk(pfw[it].x, pfw[it].y), pB = cvtpk(pfw[it].z, pfw[it].w);
            s_wT[((n0 + 0) * 64 + k) ^ (((n0 + 0) & 7) << 3)] = (ushort)pA;
            s_wT[((n0 + 1) * 64 + k) ^ (((n0 + 1) & 7) << 3)] = (ushort)(pA >> 16);
            s_wT[((n0 + 2) * 64 + k) ^ (((n0 + 2) & 7) << 3)] = (ushort)pB;
            s_wT[((n0 + 3) * 64 + k) ^ (((n0 + 3) & 7) << 3)] = (ushort)(pB >> 16);
        }
        const float be = enc_b[n];
        float v0 = fmaxf(acc[0] + be, 0.f), v1 = fmaxf(acc[1] + be, 0.f);
        float v2 = fmaxf(acc[2] + be, 0.f), v3 = fmaxf(acc[3] + be, 0.f);
        uint pA = cvtpk(v0, v1), pB = cvtpk(v2, v3);
        const int rb = rt * 16 + lg * 4;
        s_enc[((rb + 0) * 64 + n) ^ (((rb + 0) & 7) << 3)] = (ushort)pA;
        s_enc[((rb + 1) * 64 + n) ^ (((rb + 1) & 7) << 3)] = (ushort)(pA >> 16);
        s_enc[((rb + 2) * 64 + n) ^ (((rb + 2) & 7) << 3)] = (ushort)pB;
        s_enc[((rb + 3) * 64 + n) ^ (((rb + 3) & 7) << 3)] = (ushort)(pB >> 16);
    }
    __syncthreads();
    {
        f32x4 acc[3];
        #pragma unroll
        for (int q = 0; q < 3; ++q) acc[q] = (f32x4){0.f, 0.f, 0.f, 0.f};
        const int arow = rt * 16 + lr;
        #pragma unroll
        for (int ks = 0; ks < 2; ++ks) {
            const int k0 = ks * 32 + lg * 8;
            bf16x8 a = *(const bf16x8*)(s_enc + ((arow * 64 + k0) ^ ((arow & 7) << 3)));
            #pragma unroll
            for (int q = 0; q < 3; ++q) {
                const int n = (ct * 3 + q) * 16 + lr;
                bf16x8 bf = *(const bf16x8*)(s_wT + ((n * 64 + k0) ^ ((n & 7) << 3)));
                acc[q] = __builtin_amdgcn_mfma_f32_16x16x32_bf16(a, bf, acc[q], 0, 0, 0);
            }
        }
        const int rb = rt * 16 + lg * 4;
        #pragma unroll
        for (int q = 0; q < 3; ++q) {
            const int nfull = (ct * 3 + q) * 16;
            const int cc = nfull + lr;
            if (nfull < 64) {
                #pragma unroll
                for (int rr = 0; rr < 4; ++rr) {
                    const int row = rb + rr;
                    s_gi[(row * 64 + cc) ^ ((row & 7) << 2)] = acc[q][rr];
                }
            } else if (nfull < 128) {
                const float b1 = gate_b1[cc - 64];
                #pragma unroll
                for (int rr = 0; rr < 4; ++rr) {
                    const int row = rb + rr;
                    s_gj[(row * 64 + (cc - 64)) ^ ((row & 7) << 2)] = acc[q][rr] + b1;
                }
            } else {
                const float bm = msg_b1[cc - 128];
                float v0 = fmaxf(acc[q][0] + bm, 0.f), v1 = fmaxf(acc[q][1] + bm, 0.f);
                float v2 = fmaxf(acc[q][2] + bm, 0.f), v3 = fmaxf(acc[q][3] + bm, 0.f);
                uint pA = cvtpk(v0, v1), pB = cvtpk(v2, v3);
                const int c2 = cc - 128;
                s_msgh[((rb + 0) * 64 + c2) ^ (((rb + 0) & 7) << 3)] = (ushort)pA;
                s_msgh[((rb + 1) * 64 + c2) ^ (((rb + 1) & 7) << 3)] = (ushort)(pA >> 16);
                s_msgh[((rb + 2) * 64 + c2) ^ (((rb + 2) & 7) << 3)] = (ushort)pB;
                s_msgh[((rb + 3) * 64 + c2) ^ (((rb + 3) & 7) << 3)] = (ushort)(pB >> 16);
            }
        }
    }
    __syncthreads();
    {
        f32x4 acc = (f32x4){0.f, 0.f, 0.f, 0.f};
        const int arow = rt * 16 + lr;
        const int nn3 = 192 + ct * 16 + lr;
        #pragma unroll
        for (int ks = 0; ks < 2; ++ks) {
            const int k0 = ks * 32 + lg * 8;
            bf16x8 a = *(const bf16x8*)(s_msgh + ((arow * 64 + k0) ^ ((arow & 7) << 3)));
            bf16x8 bf = *(const bf16x8*)(s_wT + ((nn3 * 64 + k0) ^ ((nn3 & 7) << 3)));
            acc = __builtin_amdgcn_mfma_f32_16x16x32_bf16(a, bf, acc, 0, 0, 0);
        }
        const int h  = ct * 16 + lr;
        const int jb = rt * 16 + lg * 4;
        const float bm2 = msg_b2[h];
        uint pA = cvtpk(acc[0] + bm2, acc[1] + bm2);
        uint pB = cvtpk(acc[2] + bm2, acc[3] + bm2);
        const int e = (h * 64 + jb) ^ ((h & 7) << 3);
        *(uint*)(s_msgT + e)     = pA;
        *(uint*)(s_msgT + e + 2) = pB;
    }
    {
        const int row0g = wv * 4;
        float ag[4] = {0.f, 0.f, 0.f, 0.f};
        #pragma unroll 4
        for (int h0 = 0; h0 < 64; h0 += 4) {
            float4 gj4 = *(const float4*)&s_gj[(lane * 64 + h0) ^ ((lane & 7) << 2)];
            float4 w24 = *(const float4*)&s_w2[h0];
            #pragma unroll
            for (int r = 0; r < 4; ++r) {
                const int row = row0g + r;
                float4 gi4 = *(const float4*)&s_gi[(row * 64 + h0) ^ ((row & 7) << 2)];
                ag[r] = fmaf(fmaxf(gi4.x + gj4.x, 0.f), w24.x, ag[r]);
                ag[r] = fmaf(fmaxf(gi4.y + gj4.y, 0.f), w24.y, ag[r]);
                ag[r] = fmaf(fmaxf(gi4.z + gj4.z, 0.f), w24.z, ag[r]);
                ag[r] = fmaf(fmaxf(gi4.w + gj4.w, 0.f), w24.w, ag[r]);
            }
        }
        const float b2v = gate_b2[0];
        #pragma unroll
        for (int r = 0; r < 4; ++r) {
            const int row = row0g + r;
            const float g = 1.f / (1.f + __expf(-(ag[r] + b2v)));
            s_gatesb[(row * 64 + lane) ^ ((row & 7) << 3)] = f2b1(g);
        }
    }
    __syncthreads();
    {
        const int rtl = wv >> 2;
        const int ctl = wv & 3;
        f32x4 acc = (f32x4){0.f, 0.f, 0.f, 0.f};
        const int arow = rtl * 16 + lr;
        const int n = ctl * 16 + lr;
        #pragma unroll
        for (int ks = 0; ks < 2; ++ks) {
            const int k0 = ks * 32 + lg * 8;
            bf16x8 a  = *(const bf16x8*)(s_gatesb + ((arow * 64 + k0) ^ ((arow & 7) << 3)));
            bf16x8 bf = *(const bf16x8*)(s_msgT   + ((n * 64 + k0) ^ ((n & 7) << 3)));
            acc = __builtin_amdgcn_mfma_f32_16x16x32_bf16(a, bf, acc, 0, 0, 0);
        }
        const int rb = rtl * 16 + lg * 4;
        #pragma unroll
        for (int rr = 0; rr < 4; ++rr)
            out[((size_t)bb * 64 + rb + rr) * 64 + n] = acc[rr];
    }
}

extern "C" void kernel_launch(void* const* d_in, const int* in_sizes, int n_in,
                              void* d_out, int out_size, void* d_ws, size_t ws_size,
                              hipStream_t stream) {
    const float* obs     = (const float*)d_in[0];
    const float* enc_w   = (const float*)d_in[1];
    const float* enc_b   = (const float*)d_in[2];
    const float* gate_w1 = (const float*)d_in[3];
    const float* gate_b1 = (const float*)d_in[4];
    const float* gate_w2 = (const float*)d_in[5];
    const float* gate_b2 = (const float*)d_in[6];
    const float* msg_w1  = (const float*)d_in[7];
    const float* msg_b1  = (const float*)d_in[8];
    const float* msg_w2  = (const float*)d_in[9];
    const float* msg_b2  = (const float*)d_in[10];
    float* out = (float*)d_out;

    const size_t obs_elems = (size_t)Bb * 64 * 128;       // 2,097,152 bf16
    const size_t w_elems   = 24576;                       // encwT 8192 + wT 16384
    const size_t need = (obs_elems + w_elems) * sizeof(ushort);   // ~4.24 MB
    if (ws_size >= need) {
        ushort* obs_bf = (ushort*)d_ws;
        ushort* wimg   = obs_bf + obs_elems;
        gcm_prep<<<1036, 256, 0, stream>>>(obs, enc_w, gate_w1, msg_w1, msg_w2,
                                           obs_bf, wimg);
        gcm_main<<<Bb, 1024, 0, stream>>>(obs_bf, wimg, enc_b, gate_b1,
                                          gate_w2, gate_b2, msg_b1, msg_b2, out);
    } else {
        gcm_fb<<<Bb, 1024, 0, stream>>>(obs, enc_w, enc_b, gate_w1, gate_b1,
                                        gate_w2, gate_b2, msg_w1, msg_b1,
                                        msg_w2, msg_b2, out);
    }
}